// Round 2
// baseline (137.397 us; speedup 1.0000x reference)
//
#include <hip/hip_runtime.h>
#include <hip/hip_bf16.h>

// Problem constants
#define N_  4
#define CI  4
#define CO  8
#define HH  512
#define WW  512
#define RK  4

// x[n][i][h][w]   : ((n*CI + i)*HH + h)*WW + w
// L[o][i][p][r]   : ((o*CI + i)*HH + p)*RK + r   (float4-aligned per p)
// Rt[n][o][h]     : (n*CO + o)*HH + h
// Ct[n][o][w]     : (n*CO + o)*WW + w
// out[n][o][h][w] : ((n*CO + o)*HH + h)*WW + w

__device__ __forceinline__ float dot4(float4 a, float4 b) {
    return fmaf(a.x, b.x, fmaf(a.y, b.y, fmaf(a.z, b.z, a.w * b.w)));
}

// R~[n,o,h] = sum_{i,w} x[n,i,h,w] * dot4(L[o,i,h,:], L[o,i,w,:])
// grid (wchunk=8, htile=8, n=4), block 256 = 64 h-lanes x 4 w-strips
__global__ __launch_bounds__(256) void rowsum_kernel(
        const float* __restrict__ x, const float* __restrict__ L,
        float* __restrict__ Rt) {
    const int lane  = threadIdx.x & 63;   // h offset within tile
    const int strip = threadIdx.x >> 6;   // which 16-w strip
    const int h  = blockIdx.y * 64 + lane;
    const int wb = blockIdx.x * 64 + strip * 16;
    const int n  = blockIdx.z;

    float acc[CO];
#pragma unroll
    for (int o = 0; o < CO; ++o) acc[o] = 0.f;

    for (int i = 0; i < CI; ++i) {
        // per-lane Lh fragments (float4 each)
        float4 Lh[CO];
#pragma unroll
        for (int o = 0; o < CO; ++o)
            Lh[o] = *reinterpret_cast<const float4*>(&L[((o*CI + i)*HH + h)*RK]);

        const float* xrow = &x[((n*CI + i)*HH + h)*WW];
        // whole-cache-line reads: 4 x float4 per lane (scattered lines, fully used)
        float4 xq0 = *reinterpret_cast<const float4*>(&xrow[wb + 0]);
        float4 xq1 = *reinterpret_cast<const float4*>(&xrow[wb + 4]);
        float4 xq2 = *reinterpret_cast<const float4*>(&xrow[wb + 8]);
        float4 xq3 = *reinterpret_cast<const float4*>(&xrow[wb + 12]);

#pragma unroll
        for (int kq = 0; kq < 4; ++kq) {
            float4 xv4 = (kq == 0) ? xq0 : (kq == 1) ? xq1 : (kq == 2) ? xq2 : xq3;
            const int w0 = wb + kq * 4;
#pragma unroll
            for (int c = 0; c < 4; ++c) {
                const int w = w0 + c;
                const float xv = (c == 0) ? xv4.x : (c == 1) ? xv4.y : (c == 2) ? xv4.z : xv4.w;
#pragma unroll
                for (int o = 0; o < CO; ++o) {
                    // wave-uniform address -> broadcast load
                    float4 lw = *reinterpret_cast<const float4*>(&L[((o*CI + i)*HH + w)*RK]);
                    acc[o] = fmaf(xv, dot4(Lh[o], lw), acc[o]);
                }
            }
        }
    }
#pragma unroll
    for (int o = 0; o < CO; ++o)
        atomicAdd(&Rt[(n*CO + o)*HH + h], acc[o]);
}

// C~[n,o,w] = sum_{i,h} x[n,i,h,w] * dot4(L[o,i,h,:], L[o,i,w,:])
// grid (hchunk=8, wtile=8, n=4), block 256 = 64 w-lanes x 4 h-strips
__global__ __launch_bounds__(256) void colsum_kernel(
        const float* __restrict__ x, const float* __restrict__ L,
        float* __restrict__ Ct) {
    const int lane  = threadIdx.x & 63;   // w offset within tile
    const int strip = threadIdx.x >> 6;   // which 16-h strip
    const int w  = blockIdx.y * 64 + lane;
    const int hb = blockIdx.x * 64 + strip * 16;
    const int n  = blockIdx.z;

    float acc[CO];
#pragma unroll
    for (int o = 0; o < CO; ++o) acc[o] = 0.f;

    for (int i = 0; i < CI; ++i) {
        float4 Lw[CO];
#pragma unroll
        for (int o = 0; o < CO; ++o)
            Lw[o] = *reinterpret_cast<const float4*>(&L[((o*CI + i)*HH + w)*RK]);

        const float* xbase = &x[((n*CI + i)*HH)*WW + w];
#pragma unroll
        for (int k = 0; k < 16; ++k) {
            const int h = hb + k;
            const float xv = xbase[h * WW];   // coalesced across lanes
#pragma unroll
            for (int o = 0; o < CO; ++o) {
                float4 lh = *reinterpret_cast<const float4*>(&L[((o*CI + i)*HH + h)*RK]);
                acc[o] = fmaf(xv, dot4(Lw[o], lh), acc[o]);
            }
        }
    }
#pragma unroll
    for (int o = 0; o < CO; ++o)
        atomicAdd(&Ct[(n*CO + o)*WW + w], acc[o]);
}

// out[n,o,h,w] = R~[n,o,h] + C~[n,o,w] + bias[o] - sum_i x[n,i,h,w]*dot4(Lh,Lw)
// grid (wtile=2, htile=64, n=4), block 256 (one w per thread, 8 h rows, all o)
__global__ __launch_bounds__(256) void final_kernel(
        const float* __restrict__ x, const float* __restrict__ L,
        const float* __restrict__ Rt, const float* __restrict__ Ct,
        const float* __restrict__ bias, float* __restrict__ out) {
    const int w  = blockIdx.x * 256 + threadIdx.x;
    const int h0 = blockIdx.y * 8;
    const int n  = blockIdx.z;

    // x held in registers: read once, reused by all 8 output channels
    float xv[CI][8];
#pragma unroll
    for (int i = 0; i < CI; ++i)
#pragma unroll
        for (int hh = 0; hh < 8; ++hh)
            xv[i][hh] = x[((n*CI + i)*HH + h0 + hh)*WW + w];

#pragma unroll 2
    for (int o = 0; o < CO; ++o) {
        float4 Lw[CI];
#pragma unroll
        for (int i = 0; i < CI; ++i)
            Lw[i] = *reinterpret_cast<const float4*>(&L[((o*CI + i)*HH + w)*RK]);
        const float cv = Ct[(n*CO + o)*WW + w];
        const float bz = bias[o];
        const float* rrow = &Rt[(n*CO + o)*HH + h0];
        float* orow = &out[((n*CO + o)*HH + h0)*WW + w];
#pragma unroll
        for (int hh = 0; hh < 8; ++hh) {
            float s = rrow[hh] + cv + bz;
#pragma unroll
            for (int i = 0; i < CI; ++i) {
                float4 lh = *reinterpret_cast<const float4*>(&L[((o*CI + i)*HH + h0 + hh)*RK]);
                s = fmaf(-xv[i][hh], dot4(lh, Lw[i]), s);
            }
            orow[hh * WW] = s;
        }
    }
}

extern "C" void kernel_launch(void* const* d_in, const int* in_sizes, int n_in,
                              void* d_out, int out_size, void* d_ws, size_t ws_size,
                              hipStream_t stream) {
    const float* x    = (const float*)d_in[0];
    const float* L    = (const float*)d_in[1];
    const float* bias = (const float*)d_in[2];
    float* out = (float*)d_out;

    float* Rt = (float*)d_ws;                    // N*CO*H = 16384 floats
    float* Ct = Rt + N_*CO*HH;                   // N*CO*W = 16384 floats

    hipMemsetAsync(d_ws, 0, 2 * N_*CO*HH * sizeof(float), stream);

    rowsum_kernel<<<dim3(8, 8, 4), 256, 0, stream>>>(x, L, Rt);
    colsum_kernel<<<dim3(8, 8, 4), 256, 0, stream>>>(x, L, Ct);
    final_kernel<<<dim3(2, 64, 4), 256, 0, stream>>>(x, L, Rt, Ct, bias, out);
}